// Round 12
// baseline (188.927 us; speedup 1.0000x reference)
//
#include <hip/hip_runtime.h>

#define EMBED   1024
#define NHEADS  16
#define RANK    32
#define HDIM    64
#define BATCH   2
#define SEQ     2048
#define BSQ     (BATCH * SEQ)          // 4096 rows
#define CEXP    0.25505998f            // (1/sqrt(32)) * log2(e)

typedef __attribute__((ext_vector_type(8))) short bf16x8;   // 8 bf16 = 4 VGPRs
typedef __attribute__((ext_vector_type(4))) float f32x4;    // MFMA 16x16 acc

__device__ __forceinline__ float bf2f(unsigned short u) {
    union { unsigned int i; float f; } x; x.i = ((unsigned int)u) << 16;
    return x.f;
}
__device__ __forceinline__ unsigned short f2bf(float f) {
    union { float f; unsigned int i; } x; x.f = f;
    unsigned int r = x.i + 0x7FFFu + ((x.i >> 16) & 1u);    // RNE
    return (unsigned short)(r >> 16);
}

// async 16B/lane global->LDS copy; lptr wave-uniform (lane scatters +lane*16B)
#define ASYNC16(gp, lp) \
    __builtin_amdgcn_global_load_lds( \
        (const __attribute__((address_space(1))) void*)(gp), \
        (__attribute__((address_space(3))) void*)(lp), 16, 0, 0)

// explicit DMA drain before barriers (v11 lesson: back-edge DMAs can miss the
// compiler's vmcnt insertion; workgroup fence alone only covers lgkmcnt).
#define VMDRAIN() asm volatile("s_waitcnt vmcnt(0)" ::: "memory")

// ---------- merged prep: hs cvt + weight transposes + bias concat ----------
__global__ __launch_bounds__(256) void prep_all(
    const float* __restrict__ hs,
    const float* __restrict__ Wq, const float* __restrict__ Wk,
    const float* __restrict__ Wv, const float* __restrict__ Wo,
    const float* __restrict__ bq, const float* __restrict__ bk,
    const float* __restrict__ bv,
    unsigned short* __restrict__ hsb, unsigned short* __restrict__ wT_all,
    unsigned short* __restrict__ woT, float* __restrict__ ball)
{
    __shared__ float L[64][65];
    const int blk = blockIdx.x;
    const int t = threadIdx.x;

    if (blk < 2048) {
        const size_t i = ((size_t)blk * 256 + t) * 8;
        float4 v0 = *(const float4*)(hs + i);
        float4 v1 = *(const float4*)(hs + i + 4);
        ushort4 o0, o1;
        o0.x = f2bf(v0.x); o0.y = f2bf(v0.y); o0.z = f2bf(v0.z); o0.w = f2bf(v0.w);
        o1.x = f2bf(v1.x); o1.y = f2bf(v1.y); o1.z = f2bf(v1.z); o1.w = f2bf(v1.w);
        *(ushort4*)(hsb + i) = o0;
        *(ushort4*)(hsb + i + 4) = o1;
        return;
    }
    if (blk < 2816) {
        int idx = blk - 2048;
        int z, bx, by;
        if (idx < 256) { z = idx >> 7; int r2 = idx & 127; bx = r2 & 7; by = r2 >> 3; }
        else { idx -= 256; z = 2 + (idx >> 8); int r2 = idx & 255; bx = r2 & 15; by = r2 >> 4; }
        const int Nw = (z < 2) ? 512 : 1024;
        const float* W = (z == 0) ? Wq : (z == 1) ? Wk : (z == 2) ? Wv : Wo;
        unsigned short* dst = (z == 3) ? woT : (wT_all + (size_t)z * 512 * 1024);

        const int r = t >> 2, c0 = (t & 3) * 16;
        const float* src = W + (size_t)(by * 64 + r) * Nw + bx * 64 + c0;
        #pragma unroll
        for (int u = 0; u < 4; u++)
            *(float4*)&L[r][c0 + 4 * u] = *(const float4*)(src + 4 * u);
        __syncthreads();
        unsigned short* drow = dst + (size_t)(bx * 64 + r) * 1024 + by * 64 + c0;
        #pragma unroll
        for (int u4 = 0; u4 < 4; u4++) {
            ushort4 o;
            o.x = f2bf(L[c0 + 4 * u4 + 0][r]);
            o.y = f2bf(L[c0 + 4 * u4 + 1][r]);
            o.z = f2bf(L[c0 + 4 * u4 + 2][r]);
            o.w = f2bf(L[c0 + 4 * u4 + 3][r]);
            *(ushort4*)(drow + 4 * u4) = o;
        }
        return;
    }
    {
        const int i = (blk - 2816) * 256 + t;
        ball[i] = (i < 512) ? bq[i] : (i < 1024) ? bk[i - 512] : bv[i - 1024];
    }
}

// ---------- QKV MFMA GEMM: 128x128 tiles, BK=128 + LDS-bounce epilogue -----
// R11 (BK=128, half barriers) confirmed +5us. R12: the qH/kH epilogue was 64
// scalar 2B global stores/thread (~4M scattered stores over 256 blocks, the
// [bh][s][32] layout puts a thread's values at 64B stride). Fix: reuse the
// dead 64KB As/Bs as a [128][136] bf16 bounce tile (pitch 136: 16B-aligned
// rows, scalar-write banks 2-way=free), then store coalesced ushort8 chunks
// (store instrs 64->16/thread, 2B->8B each). Values bit-identical. vT path
// (already 8B stores) unchanged.
__global__ __launch_bounds__(256) void gemm_qkv(
    const unsigned short* __restrict__ A, const unsigned short* __restrict__ BT,
    const float* __restrict__ bias,
    unsigned short* __restrict__ qH, unsigned short* __restrict__ kH,
    unsigned short* __restrict__ vTout)
{
    __shared__ unsigned short SM[32768];          // 64 KB: As | Bs, then W
    unsigned short* As = SM;                      // 4*128*32 = 16384 u16
    unsigned short* Bs = SM + 16384;
    const int K = 1024;
    const int t = threadIdx.x;
    const int lane = t & 63;
    const int li = lane & 15, la = lane >> 4;
    const int w = t >> 6, wm = w >> 1, wn = w & 1;
    const int row0 = blockIdx.y * 128, col0 = blockIdx.x * 128;

    const int sr = lane >> 2, sc2 = (lane & 3) * 8;    // 16 rows / instr
    const unsigned short* ag = A + (size_t)(row0 + sr) * K + sc2;
    const unsigned short* bg = BT + (size_t)(col0 + sr) * K + sc2;

    f32x4 acc[4][4];
    #pragma unroll
    for (int i = 0; i < 4; i++)
        #pragma unroll
        for (int j = 0; j < 4; j++)
            acc[i][j] = (f32x4){0.f, 0.f, 0.f, 0.f};

    for (int k0 = 0; k0 < K; k0 += 128) {
        #pragma unroll
        for (int kh = 0; kh < 4; kh++)
            #pragma unroll
            for (int u = 0; u < 2; u++) {
                const int ro = w * 32 + u * 16;
                ASYNC16(ag + (size_t)ro * K + k0 + kh * 32, &As[kh * 4096 + ro * 32]);
                ASYNC16(bg + (size_t)ro * K + k0 + kh * 32, &Bs[kh * 4096 + ro * 32]);
            }
        __syncthreads();
        #pragma unroll
        for (int kh = 0; kh < 4; kh++) {
            bf16x8 af[4], bfr[4];
            #pragma unroll
            for (int mt = 0; mt < 4; mt++)
                af[mt] = *(const bf16x8*)&As[kh * 4096 + (wm * 64 + mt * 16 + li) * 32 + la * 8];
            #pragma unroll
            for (int nt = 0; nt < 4; nt++)
                bfr[nt] = *(const bf16x8*)&Bs[kh * 4096 + (wn * 64 + nt * 16 + li) * 32 + la * 8];
            #pragma unroll
            for (int mt = 0; mt < 4; mt++)
                #pragma unroll
                for (int nt = 0; nt < 4; nt++)
                    acc[mt][nt] = __builtin_amdgcn_mfma_f32_16x16x32_bf16(af[mt], bfr[nt], acc[mt][nt], 0, 0, 0);
        }
        __syncthreads();
    }

    const int bb = row0 >> 11;               // batch (tile never crosses)
    if (col0 < 1024) {
        // ---- qH/kH blocks: bounce through LDS, store coalesced ----
        unsigned short* Wb = SM;             // [128][136] u16 = 34816 B
        const int WP = 136;
        #pragma unroll
        for (int nt = 0; nt < 4; nt++) {
            const int c = wn * 64 + nt * 16 + li;
            const float bval = bias[col0 + c];
            #pragma unroll
            for (int mt = 0; mt < 4; mt++)
                #pragma unroll
                for (int r = 0; r < 4; r++)
                    Wb[(wm * 64 + mt * 16 + la * 4 + r) * WP + c] =
                        f2bf(acc[mt][nt][r] + bval);
        }
        __syncthreads();
        const int jb0 = row0 & 2047;
        #pragma unroll
        for (int k = 0; k < 8; k++) {
            const int id = k * 256 + t;      // 0..2047
            const int s  = id >> 4;          // local row 0..127
            const int c  = (id & 15) * 8;    // local col 0..120 (8-aligned)
            const int col = col0 + c;
            const int hh = (col & 511) >> 5;
            unsigned short* dst = ((col < 512) ? qH : kH)
                + ((size_t)(bb * 16 + hh) * 2048 + jb0 + s) * 32 + (c & 31);
            *(ushort4*)dst       = *(const ushort4*)&Wb[s * WP + c];
            *(ushort4*)(dst + 4) = *(const ushort4*)&Wb[s * WP + c + 4];
        }
        return;
    }
    // ---- vT blocks: unchanged R11 path (already 8B stores) ----
    const int jb = (row0 & 2047) + wm * 64;
    #pragma unroll
    for (int nt = 0; nt < 4; nt++) {
        const int col = col0 + wn * 64 + nt * 16 + li;
        const float bval = bias[col];
        const int hd = col - 1024;
        unsigned short* dcol = vTout + ((size_t)(bb * 16 + (hd >> 6)) * 64 + (hd & 63)) * SEQ;
        #pragma unroll
        for (int mt = 0; mt < 4; mt++) {
            const int srow = jb + mt * 16 + la * 4;
            ushort4 o;
            o.x = f2bf(acc[mt][nt][0] + bval);
            o.y = f2bf(acc[mt][nt][1] + bval);
            o.z = f2bf(acc[mt][nt][2] + bval);
            o.w = f2bf(acc[mt][nt][3] + bval);
            *(ushort4*)(dcol + srow) = o;
        }
    }
}

// ---------- out-proj GEMM: 64x128 tiles, BK=128 (8 iters) ------------------
__global__ __launch_bounds__(256) void gemm_out(
    const unsigned short* __restrict__ A, const unsigned short* __restrict__ BT,
    const float* __restrict__ bias, float* __restrict__ C)
{
    __shared__ unsigned short As[4 * 64 * 32];    // 16 KB
    __shared__ unsigned short Bs[4 * 128 * 32];   // 32 KB
    const int K = 1024;
    const int t = threadIdx.x;
    const int lane = t & 63;
    const int li = lane & 15, la = lane >> 4;
    const int w = t >> 6, wm = w >> 1, wn = w & 1;
    const int row0 = blockIdx.y * 64, col0 = blockIdx.x * 128;

    const int sr = lane >> 2, sc2 = (lane & 3) * 8;
    const unsigned short* ag = A + (size_t)(row0 + sr) * K + sc2;
    const unsigned short* bg = BT + (size_t)(col0 + sr) * K + sc2;

    f32x4 acc[2][4];
    #pragma unroll
    for (int i = 0; i < 2; i++)
        #pragma unroll
        for (int j = 0; j < 4; j++)
            acc[i][j] = (f32x4){0.f, 0.f, 0.f, 0.f};

    for (int k0 = 0; k0 < K; k0 += 128) {
        #pragma unroll
        for (int kh = 0; kh < 4; kh++) {
            // A: 64 rows -> wave w stages rows w*16..+15 per kh
            ASYNC16(ag + (size_t)(w * 16) * K + k0 + kh * 32, &As[kh * 2048 + (w * 16) * 32]);
            // B: 128 rows -> wave w stages rows w*32+u*16
            #pragma unroll
            for (int u = 0; u < 2; u++) {
                const int ro = w * 32 + u * 16;
                ASYNC16(bg + (size_t)ro * K + k0 + kh * 32, &Bs[kh * 4096 + ro * 32]);
            }
        }
        __syncthreads();
        #pragma unroll
        for (int kh = 0; kh < 4; kh++) {
            bf16x8 af[2], bfr[4];
            #pragma unroll
            for (int mt = 0; mt < 2; mt++)
                af[mt] = *(const bf16x8*)&As[kh * 2048 + (wm * 32 + mt * 16 + li) * 32 + la * 8];
            #pragma unroll
            for (int nt = 0; nt < 4; nt++)
                bfr[nt] = *(const bf16x8*)&Bs[kh * 4096 + (wn * 64 + nt * 16 + li) * 32 + la * 8];
            #pragma unroll
            for (int mt = 0; mt < 2; mt++)
                #pragma unroll
                for (int nt = 0; nt < 4; nt++)
                    acc[mt][nt] = __builtin_amdgcn_mfma_f32_16x16x32_bf16(af[mt], bfr[nt], acc[mt][nt], 0, 0, 0);
        }
        __syncthreads();
    }

    #pragma unroll
    for (int nt = 0; nt < 4; nt++) {
        const int col = col0 + wn * 64 + nt * 16 + li;
        const float bval = bias[col];
        #pragma unroll
        for (int mt = 0; mt < 2; mt++)
            #pragma unroll
            for (int r = 0; r < 4; r++) {
                const int row = row0 + wm * 32 + mt * 16 + la * 4 + r;
                C[(size_t)row * 1024 + col] = acc[mt][nt][r] + bval;
            }
    }
}

// ---------- MFMA flash attention v15 (best measured: 48.9 us) -------------
// 128-thread blocks, wave owns 32 i-rows (2 Q frags); K/V via global_load_lds
// into XOR-swizzled linear tiles, dbuf, VMDRAIN; VALU rowsum (no vones MFMA);
// s_setprio around MFMA clusters.
__global__ __launch_bounds__(128) void attn_v15(
    const unsigned short* __restrict__ qH,
    const unsigned short* __restrict__ kH,
    const unsigned short* __restrict__ vT,
    unsigned short* __restrict__ ao)
{
    __shared__ unsigned short kt[2][64 * 32];   //  8 KB
    __shared__ unsigned short vt[2][64 * 64];   // 16 KB
    __shared__ unsigned short P[64 * 72];       //  9 KB

    const int t = threadIdx.x;
    const int lane = t & 63;
    const int li = lane & 15, la = lane >> 4;
    const int w = t >> 6;                       // 0..1

    const int bh = blockIdx.x & 31;
    const int itile = blockIdx.x >> 5;
    const int i0 = itile * 64;
    const int b = bh >> 4, h = bh & 15;

    // two Q frags (B-operand: n=i=w*32+iq*16+li, k=la*8..+7), CEXP folded
    bf16x8 qf[2];
    #pragma unroll
    for (int iq = 0; iq < 2; iq++) {
        const unsigned short* qp = qH + ((size_t)bh * 2048 + i0 + w * 32 + iq * 16 + li) * 32 + la * 8;
        ushort4 q0 = *(const ushort4*)qp;
        ushort4 q1 = *(const ushort4*)(qp + 4);
        short u[8];
        u[0] = (short)f2bf(bf2f(q0.x) * CEXP);
        u[1] = (short)f2bf(bf2f(q0.y) * CEXP);
        u[2] = (short)f2bf(bf2f(q0.z) * CEXP);
        u[3] = (short)f2bf(bf2f(q0.w) * CEXP);
        u[4] = (short)f2bf(bf2f(q1.x) * CEXP);
        u[5] = (short)f2bf(bf2f(q1.y) * CEXP);
        u[6] = (short)f2bf(bf2f(q1.z) * CEXP);
        u[7] = (short)f2bf(bf2f(q1.w) * CEXP);
        qf[iq] = *(const bf16x8*)u;
    }

    // ---- async staging addresses (per-lane global, swizzled source) ----
    const int cK8 = ((lane & 3) ^ ((lane >> 3) & 3)) * 8;
    const unsigned short* kpt = kH + (size_t)bh * 2048 * 32
                               + (size_t)(w * 32 + (lane >> 2)) * 32 + cK8;
    const int rV = lane >> 3;
    const int cV8 = ((lane & 7) ^ rV) * 8;
    const unsigned short* vpt = vT + ((size_t)bh * 64 + w * 32 + rV) * SEQ + cV8;

    // ---- swizzled read column offsets (const per thread) ----
    const int kcol  = (la ^ ((li >> 1) & 3)) * 8;          // K read chunk
    const int vcol0 = ((0 * 4 + la) ^ (li & 7)) * 8;       // V read, ks=0
    const int vcol1 = ((1 * 4 + la) ^ (li & 7)) * 8;       // V read, ks=1

    f32x4 accO[2][4];
    float lsum0 = 0.f, lsum1 = 0.f;             // row-sum for i=li, per iq
    #pragma unroll
    for (int iq = 0; iq < 2; iq++)
        #pragma unroll
        for (int dt = 0; dt < 4; dt++) accO[iq][dt] = (f32x4){0.f, 0.f, 0.f, 0.f};
    const int prow0 = w * 32 + li;
    const int prow1 = prow0 + 16;

    // prologue: issue async stage of tile 0 -> buf0 (drained at first barrier)
    ASYNC16(kpt,            &kt[0][(w * 32) * 32]);
    ASYNC16(kpt + 16 * 32,  &kt[0][(w * 32 + 16) * 32]);
    #pragma unroll
    for (int q = 0; q < 4; q++)
        ASYNC16(vpt + (size_t)q * 8 * SEQ, &vt[0][(w * 32 + q * 8) * 64]);

    #define ATTN_BODY(BUF, OTHER, JPRE)                                            \
    {                                                                              \
        VMDRAIN();                                                                 \
        __syncthreads();                                                           \
        const int jn = (JPRE) & 2047;                                              \
        ASYNC16(kpt + (size_t)jn * 32,           &kt[OTHER][(w * 32) * 32]);       \
        ASYNC16(kpt + (size_t)jn * 32 + 16 * 32, &kt[OTHER][(w * 32 + 16) * 32]);  \
        _Pragma("unroll")                                                          \
        for (int q = 0; q < 4; q++)                                                \
            ASYNC16(vpt + jn + (size_t)q * 8 * SEQ, &vt[OTHER][(w * 32 + q * 8) * 64]); \
        bf16x8 kf[4];                                                              \
        _Pragma("unroll")                                                          \
        for (int jt = 0; jt < 4; jt++)                                             \
            kf[jt] = *(const bf16x8*)&kt[BUF][(jt * 16 + li) * 32 + kcol];         \
        f32x4 sc0[4], sc1[4];                                                      \
        __builtin_amdgcn_s_setprio(1);                                             \
        _Pragma("unroll")                                                          \
        for (int jt = 0; jt < 4; jt++) {                                           \
            sc0[jt] = __builtin_amdgcn_mfma_f32_16x16x32_bf16(kf[jt], qf[0], (f32x4){0.f,0.f,0.f,0.f}, 0, 0, 0); \
            sc1[jt] = __builtin_amdgcn_mfma_f32_16x16x32_bf16(kf[jt], qf[1], (f32x4){0.f,0.f,0.f,0.f}, 0, 0, 0); \
        }                                                                          \
        __builtin_amdgcn_s_setprio(0);                                             \
        _Pragma("unroll")                                                          \
        for (int jt = 0; jt < 4; jt++) {                                           \
            float e0 = __builtin_amdgcn_exp2f(sc0[jt][0]);                         \
            float e1 = __builtin_amdgcn_exp2f(sc0[jt][1]);                         \
            float e2 = __builtin_amdgcn_exp2f(sc0[jt][2]);                         \
            float e3 = __builtin_amdgcn_exp2f(sc0[jt][3]);                         \
            lsum0 += (e0 + e1) + (e2 + e3);                                        \
            uint2 pk;                                                              \
            asm("v_cvt_pk_bf16_f32 %0, %1, %2" : "=v"(pk.x) : "v"(e0), "v"(e1));   \
            asm("v_cvt_pk_bf16_f32 %0, %1, %2" : "=v"(pk.y) : "v"(e2), "v"(e3));   \
            *(uint2*)&P[prow0 * 72 + jt * 16 + la * 4] = pk;                       \
        }                                                                          \
        _Pragma("unroll")                                                          \
        for (int jt = 0; jt < 4; jt++) {                                           \
            float e0 = __builtin_amdgcn_exp2f(sc1[jt][0]);                         \
            float e1 = __builtin_amdgcn_exp2f(sc1[jt][1]);                         \
            float e2 = __builtin_amdgcn_exp2f(sc1[jt][2]);                         \
            float e3 = __builtin_amdgcn_exp2f(sc1[jt][3]);                         \
            lsum1 += (e0 + e1) + (e2 + e3);                                        \
            uint2 pk;                                                              \
            asm("v_cvt_pk_bf16_f32 %0, %1, %2" : "=v"(pk.x) : "v"(e0), "v"(e1));   \
            asm("v_cvt_pk_bf16_f32 %0, %1, %2" : "=v"(pk.y) : "v"(e2), "v"(e3));   \
            *(uint2*)&P[prow1 * 72 + jt * 16 + la * 4] = pk;                       \
        }                                                                          \
        _Pragma("unroll")                                                          \
        for (int ks = 0; ks < 2; ks++) {                                           \
            const bf16x8 pf0 = *(const bf16x8*)&P[prow0 * 72 + ks * 32 + la * 8];  \
            const bf16x8 pf1 = *(const bf16x8*)&P[prow1 * 72 + ks * 32 + la * 8];  \
            const int vcol = ks ? vcol1 : vcol0;                                   \
            __builtin_amdgcn_s_setprio(1);                                         \
            _Pragma("unroll")                                                      \
            for (int dt = 0; dt < 4; dt++) {                                       \
                const bf16x8 vf = *(const bf16x8*)&vt[BUF][(dt * 16 + li) * 64 + vcol]; \
                accO[0][dt] = __builtin_amdgcn_mfma_f32_16x16x32_bf16(pf0, vf, accO[0][dt], 0, 0, 0); \
                accO[1][dt] = __builtin_amdgcn_mfma_f32_16x16x32_bf16(pf1, vf, accO[1][dt], 0, 0, 0); \
            }                                                                      \
            __builtin_amdgcn_s_setprio(0);                                         \
        }                                                                          \
    }

    for (int j0 = 0; j0 < SEQ; j0 += 128) {
        ATTN_BODY(0, 1, j0 + 64)
        ATTN_BODY(1, 0, j0 + 128)
    }
    #undef ATTN_BODY

    // drain the final tile's in-flight DMAs before LDS can be reassigned
    VMDRAIN();
    __syncthreads();

    // cross-la reduce: after this every lane holds l for i = w*32+iq*16+li
    lsum0 += __shfl_xor(lsum0, 16);
    lsum0 += __shfl_xor(lsum0, 32);
    lsum1 += __shfl_xor(lsum1, 16);
    lsum1 += __shfl_xor(lsum1, 32);

    // epilogue: accO rows are m = la*4+r; fetch l from the lane holding that i
    #pragma unroll
    for (int iq = 0; iq < 2; iq++) {
        const float ls = iq ? lsum1 : lsum0;
        float linv[4];
        #pragma unroll
        for (int r = 0; r < 4; r++)
            linv[r] = 1.f / __shfl(ls, la * 4 + r);
        #pragma unroll
        for (int dt = 0; dt < 4; dt++)
            #pragma unroll
            for (int r = 0; r < 4; r++) {
                const int row = b * SEQ + i0 + w * 32 + iq * 16 + la * 4 + r;
                ao[(size_t)row * 1024 + h * 64 + dt * 16 + li] = f2bf(accO[iq][dt][r] * linv[r]);
            }
    }
}

extern "C" void kernel_launch(void* const* d_in, const int* in_sizes, int n_in,
                              void* d_out, int out_size, void* d_ws, size_t ws_size,
                              hipStream_t stream) {
    const float* hs = (const float*)d_in[0];
    const float* Wq = (const float*)d_in[1];
    const float* bq = (const float*)d_in[2];
    const float* Wk = (const float*)d_in[3];
    const float* bk = (const float*)d_in[4];
    const float* Wv = (const float*)d_in[5];
    const float* bv = (const float*)d_in[6];
    const float* Wo = (const float*)d_in[7];
    const float* bo = (const float*)d_in[8];

    char* p = (char*)d_ws;                                        // 38 MB total
    unsigned short* hsb = (unsigned short*)(p);                   //  8 MB
    unsigned short* wT  = (unsigned short*)(p + 8388608u);        //  4 MB
    unsigned short* woT = (unsigned short*)(p + 12582912u);       //  2 MB
    float*          ball= (float*)(p + 14680064u);                //  8 KB
    unsigned short* qHb = (unsigned short*)(p + 14688256u);       //  4 MB
    unsigned short* kHb = (unsigned short*)(p + 18882560u);       //  4 MB
    unsigned short* vTb = (unsigned short*)(p + 23076864u);       //  8 MB
    unsigned short* ao  = (unsigned short*)(p + 31465472u);       //  8 MB

    prep_all<<<dim3(2824), 256, 0, stream>>>(hs, Wq, Wk, Wv, Wo, bq, bk, bv,
                                             hsb, wT, woT, ball);

    gemm_qkv<<<dim3(16, 32), 256, 0, stream>>>(hsb, wT, ball, qHb, kHb, vTb);

    attn_v15<<<dim3(1024), 128, 0, stream>>>(qHb, kHb, vTb, ao);

    gemm_out<<<dim3(8, 64), 256, 0, stream>>>(ao, woT, bo, (float*)d_out);
}

// Round 14
// 172.677 us; speedup vs baseline: 1.0941x; 1.0941x over previous
//
#include <hip/hip_runtime.h>

#define EMBED   1024
#define NHEADS  16
#define RANK    32
#define HDIM    64
#define BATCH   2
#define SEQ     2048
#define BSQ     (BATCH * SEQ)          // 4096 rows
#define CEXP    0.25505998f            // (1/sqrt(32)) * log2(e)

typedef __attribute__((ext_vector_type(8))) short bf16x8;   // 8 bf16 = 4 VGPRs
typedef __attribute__((ext_vector_type(4))) float f32x4;    // MFMA 16x16 acc

__device__ __forceinline__ float bf2f(unsigned short u) {
    union { unsigned int i; float f; } x; x.i = ((unsigned int)u) << 16;
    return x.f;
}
__device__ __forceinline__ unsigned short f2bf(float f) {
    union { float f; unsigned int i; } x; x.f = f;
    unsigned int r = x.i + 0x7FFFu + ((x.i >> 16) & 1u);    // RNE
    return (unsigned short)(r >> 16);
}

// async 16B/lane global->LDS copy; lptr wave-uniform (lane scatters +lane*16B)
#define ASYNC16(gp, lp) \
    __builtin_amdgcn_global_load_lds( \
        (const __attribute__((address_space(1))) void*)(gp), \
        (__attribute__((address_space(3))) void*)(lp), 16, 0, 0)

// explicit DMA drain before barriers (v11 lesson: back-edge DMAs can miss the
// compiler's vmcnt insertion; workgroup fence alone only covers lgkmcnt).
#define VMDRAIN() asm volatile("s_waitcnt vmcnt(0)" ::: "memory")

// ---------- merged prep: hs cvt + weight transposes + bias concat ----------
__global__ __launch_bounds__(256) void prep_all(
    const float* __restrict__ hs,
    const float* __restrict__ Wq, const float* __restrict__ Wk,
    const float* __restrict__ Wv, const float* __restrict__ Wo,
    const float* __restrict__ bq, const float* __restrict__ bk,
    const float* __restrict__ bv,
    unsigned short* __restrict__ hsb, unsigned short* __restrict__ wT_all,
    unsigned short* __restrict__ woT, float* __restrict__ ball)
{
    __shared__ float L[64][65];
    const int blk = blockIdx.x;
    const int t = threadIdx.x;

    if (blk < 2048) {
        const size_t i = ((size_t)blk * 256 + t) * 8;
        float4 v0 = *(const float4*)(hs + i);
        float4 v1 = *(const float4*)(hs + i + 4);
        ushort4 o0, o1;
        o0.x = f2bf(v0.x); o0.y = f2bf(v0.y); o0.z = f2bf(v0.z); o0.w = f2bf(v0.w);
        o1.x = f2bf(v1.x); o1.y = f2bf(v1.y); o1.z = f2bf(v1.z); o1.w = f2bf(v1.w);
        *(ushort4*)(hsb + i) = o0;
        *(ushort4*)(hsb + i + 4) = o1;
        return;
    }
    if (blk < 2816) {
        int idx = blk - 2048;
        int z, bx, by;
        if (idx < 256) { z = idx >> 7; int r2 = idx & 127; bx = r2 & 7; by = r2 >> 3; }
        else { idx -= 256; z = 2 + (idx >> 8); int r2 = idx & 255; bx = r2 & 15; by = r2 >> 4; }
        const int Nw = (z < 2) ? 512 : 1024;
        const float* W = (z == 0) ? Wq : (z == 1) ? Wk : (z == 2) ? Wv : Wo;
        unsigned short* dst = (z == 3) ? woT : (wT_all + (size_t)z * 512 * 1024);

        const int r = t >> 2, c0 = (t & 3) * 16;
        const float* src = W + (size_t)(by * 64 + r) * Nw + bx * 64 + c0;
        #pragma unroll
        for (int u = 0; u < 4; u++)
            *(float4*)&L[r][c0 + 4 * u] = *(const float4*)(src + 4 * u);
        __syncthreads();
        unsigned short* drow = dst + (size_t)(bx * 64 + r) * 1024 + by * 64 + c0;
        #pragma unroll
        for (int u4 = 0; u4 < 4; u4++) {
            ushort4 o;
            o.x = f2bf(L[c0 + 4 * u4 + 0][r]);
            o.y = f2bf(L[c0 + 4 * u4 + 1][r]);
            o.z = f2bf(L[c0 + 4 * u4 + 2][r]);
            o.w = f2bf(L[c0 + 4 * u4 + 3][r]);
            *(ushort4*)(drow + 4 * u4) = o;
        }
        return;
    }
    {
        const int i = (blk - 2816) * 256 + t;
        ball[i] = (i < 512) ? bq[i] : (i < 1024) ? bk[i - 512] : bv[i - 1024];
    }
}

// ---------- QKV MFMA GEMM: 128x128 tiles, BK=128 (8 iters, half barriers) --
// R11 confirmed: BK=64->128 halves rendezvous/drain events, -5us total.
// R12's LDS-bounce epilogue REGRESSED (+15us): the scalar-store epilogue's
// per-instruction pattern is already 4x32B coalesced; the bounce added an
// LDS round-trip + 2 tail barriers + 4-way-conflict writes. Reverted.
__global__ __launch_bounds__(256) void gemm_qkv(
    const unsigned short* __restrict__ A, const unsigned short* __restrict__ BT,
    const float* __restrict__ bias,
    unsigned short* __restrict__ qH, unsigned short* __restrict__ kH,
    unsigned short* __restrict__ vTout)
{
    __shared__ unsigned short As[4 * 128 * 32];   // 32 KB
    __shared__ unsigned short Bs[4 * 128 * 32];   // 32 KB
    const int K = 1024;
    const int t = threadIdx.x;
    const int lane = t & 63;
    const int li = lane & 15, la = lane >> 4;
    const int w = t >> 6, wm = w >> 1, wn = w & 1;
    const int row0 = blockIdx.y * 128, col0 = blockIdx.x * 128;

    const int sr = lane >> 2, sc2 = (lane & 3) * 8;    // 16 rows / instr
    const unsigned short* ag = A + (size_t)(row0 + sr) * K + sc2;
    const unsigned short* bg = BT + (size_t)(col0 + sr) * K + sc2;

    f32x4 acc[4][4];
    #pragma unroll
    for (int i = 0; i < 4; i++)
        #pragma unroll
        for (int j = 0; j < 4; j++)
            acc[i][j] = (f32x4){0.f, 0.f, 0.f, 0.f};

    for (int k0 = 0; k0 < K; k0 += 128) {
        #pragma unroll
        for (int kh = 0; kh < 4; kh++)
            #pragma unroll
            for (int u = 0; u < 2; u++) {
                const int ro = w * 32 + u * 16;
                ASYNC16(ag + (size_t)ro * K + k0 + kh * 32, &As[kh * 4096 + ro * 32]);
                ASYNC16(bg + (size_t)ro * K + k0 + kh * 32, &Bs[kh * 4096 + ro * 32]);
            }
        __syncthreads();
        #pragma unroll
        for (int kh = 0; kh < 4; kh++) {
            bf16x8 af[4], bfr[4];
            #pragma unroll
            for (int mt = 0; mt < 4; mt++)
                af[mt] = *(const bf16x8*)&As[kh * 4096 + (wm * 64 + mt * 16 + li) * 32 + la * 8];
            #pragma unroll
            for (int nt = 0; nt < 4; nt++)
                bfr[nt] = *(const bf16x8*)&Bs[kh * 4096 + (wn * 64 + nt * 16 + li) * 32 + la * 8];
            #pragma unroll
            for (int mt = 0; mt < 4; mt++)
                #pragma unroll
                for (int nt = 0; nt < 4; nt++)
                    acc[mt][nt] = __builtin_amdgcn_mfma_f32_16x16x32_bf16(af[mt], bfr[nt], acc[mt][nt], 0, 0, 0);
        }
        __syncthreads();
    }

    const int bb = row0 >> 11;               // batch (tile never crosses)
    const int jb = (row0 & 2047) + wm * 64;
    #pragma unroll
    for (int nt = 0; nt < 4; nt++) {
        const int col = col0 + wn * 64 + nt * 16 + li;
        const float bval = bias[col];
        if (col < 1024) {
            const int hh = (col & 511) >> 5;
            const int rr = col & 31;
            unsigned short* base = ((col < 512) ? qH : kH)
                + ((size_t)(bb * 16 + hh) * 2048) * 32 + rr;
            #pragma unroll
            for (int mt = 0; mt < 4; mt++)
                #pragma unroll
                for (int r = 0; r < 4; r++)
                    base[(size_t)(jb + mt * 16 + la * 4 + r) * 32] =
                        f2bf(acc[mt][nt][r] + bval);
        } else {
            const int hd = col - 1024;
            unsigned short* dcol = vTout + ((size_t)(bb * 16 + (hd >> 6)) * 64 + (hd & 63)) * SEQ;
            #pragma unroll
            for (int mt = 0; mt < 4; mt++) {
                const int srow = jb + mt * 16 + la * 4;
                ushort4 o;
                o.x = f2bf(acc[mt][nt][0] + bval);
                o.y = f2bf(acc[mt][nt][1] + bval);
                o.z = f2bf(acc[mt][nt][2] + bval);
                o.w = f2bf(acc[mt][nt][3] + bval);
                *(ushort4*)(dcol + srow) = o;
            }
        }
    }
}

// ---------- out-proj GEMM: 64x128 tiles, BK=128 (8 iters) ------------------
// Same barrier-halving. LDS 48 KB -> 3 blocks/CU >= the 2 the grid provides.
__global__ __launch_bounds__(256) void gemm_out(
    const unsigned short* __restrict__ A, const unsigned short* __restrict__ BT,
    const float* __restrict__ bias, float* __restrict__ C)
{
    __shared__ unsigned short As[4 * 64 * 32];    // 16 KB
    __shared__ unsigned short Bs[4 * 128 * 32];   // 32 KB
    const int K = 1024;
    const int t = threadIdx.x;
    const int lane = t & 63;
    const int li = lane & 15, la = lane >> 4;
    const int w = t >> 6, wm = w >> 1, wn = w & 1;
    const int row0 = blockIdx.y * 64, col0 = blockIdx.x * 128;

    const int sr = lane >> 2, sc2 = (lane & 3) * 8;
    const unsigned short* ag = A + (size_t)(row0 + sr) * K + sc2;
    const unsigned short* bg = BT + (size_t)(col0 + sr) * K + sc2;

    f32x4 acc[2][4];
    #pragma unroll
    for (int i = 0; i < 2; i++)
        #pragma unroll
        for (int j = 0; j < 4; j++)
            acc[i][j] = (f32x4){0.f, 0.f, 0.f, 0.f};

    for (int k0 = 0; k0 < K; k0 += 128) {
        #pragma unroll
        for (int kh = 0; kh < 4; kh++) {
            // A: 64 rows -> wave w stages rows w*16..+15 per kh
            ASYNC16(ag + (size_t)(w * 16) * K + k0 + kh * 32, &As[kh * 2048 + (w * 16) * 32]);
            // B: 128 rows -> wave w stages rows w*32+u*16
            #pragma unroll
            for (int u = 0; u < 2; u++) {
                const int ro = w * 32 + u * 16;
                ASYNC16(bg + (size_t)ro * K + k0 + kh * 32, &Bs[kh * 4096 + ro * 32]);
            }
        }
        __syncthreads();
        #pragma unroll
        for (int kh = 0; kh < 4; kh++) {
            bf16x8 af[2], bfr[4];
            #pragma unroll
            for (int mt = 0; mt < 2; mt++)
                af[mt] = *(const bf16x8*)&As[kh * 2048 + (wm * 32 + mt * 16 + li) * 32 + la * 8];
            #pragma unroll
            for (int nt = 0; nt < 4; nt++)
                bfr[nt] = *(const bf16x8*)&Bs[kh * 4096 + (wn * 64 + nt * 16 + li) * 32 + la * 8];
            #pragma unroll
            for (int mt = 0; mt < 2; mt++)
                #pragma unroll
                for (int nt = 0; nt < 4; nt++)
                    acc[mt][nt] = __builtin_amdgcn_mfma_f32_16x16x32_bf16(af[mt], bfr[nt], acc[mt][nt], 0, 0, 0);
        }
        __syncthreads();
    }

    #pragma unroll
    for (int nt = 0; nt < 4; nt++) {
        const int col = col0 + wn * 64 + nt * 16 + li;
        const float bval = bias[col];
        #pragma unroll
        for (int mt = 0; mt < 2; mt++)
            #pragma unroll
            for (int r = 0; r < 4; r++) {
                const int row = row0 + wm * 32 + mt * 16 + la * 4 + r;
                C[(size_t)row * 1024 + col] = acc[mt][nt][r] + bval;
            }
    }
}

// ---------- MFMA flash attention v15 (best measured: 48.9 us) -------------
// 128-thread blocks, wave owns 32 i-rows (2 Q frags); K/V via global_load_lds
// into XOR-swizzled linear tiles, dbuf, VMDRAIN; VALU rowsum (no vones MFMA);
// s_setprio around MFMA clusters.
__global__ __launch_bounds__(128) void attn_v15(
    const unsigned short* __restrict__ qH,
    const unsigned short* __restrict__ kH,
    const unsigned short* __restrict__ vT,
    unsigned short* __restrict__ ao)
{
    __shared__ unsigned short kt[2][64 * 32];   //  8 KB
    __shared__ unsigned short vt[2][64 * 64];   // 16 KB
    __shared__ unsigned short P[64 * 72];       //  9 KB

    const int t = threadIdx.x;
    const int lane = t & 63;
    const int li = lane & 15, la = lane >> 4;
    const int w = t >> 6;                       // 0..1

    const int bh = blockIdx.x & 31;
    const int itile = blockIdx.x >> 5;
    const int i0 = itile * 64;
    const int b = bh >> 4, h = bh & 15;

    // two Q frags (B-operand: n=i=w*32+iq*16+li, k=la*8..+7), CEXP folded
    bf16x8 qf[2];
    #pragma unroll
    for (int iq = 0; iq < 2; iq++) {
        const unsigned short* qp = qH + ((size_t)bh * 2048 + i0 + w * 32 + iq * 16 + li) * 32 + la * 8;
        ushort4 q0 = *(const ushort4*)qp;
        ushort4 q1 = *(const ushort4*)(qp + 4);
        short u[8];
        u[0] = (short)f2bf(bf2f(q0.x) * CEXP);
        u[1] = (short)f2bf(bf2f(q0.y) * CEXP);
        u[2] = (short)f2bf(bf2f(q0.z) * CEXP);
        u[3] = (short)f2bf(bf2f(q0.w) * CEXP);
        u[4] = (short)f2bf(bf2f(q1.x) * CEXP);
        u[5] = (short)f2bf(bf2f(q1.y) * CEXP);
        u[6] = (short)f2bf(bf2f(q1.z) * CEXP);
        u[7] = (short)f2bf(bf2f(q1.w) * CEXP);
        qf[iq] = *(const bf16x8*)u;
    }

    // ---- async staging addresses (per-lane global, swizzled source) ----
    const int cK8 = ((lane & 3) ^ ((lane >> 3) & 3)) * 8;
    const unsigned short* kpt = kH + (size_t)bh * 2048 * 32
                               + (size_t)(w * 32 + (lane >> 2)) * 32 + cK8;
    const int rV = lane >> 3;
    const int cV8 = ((lane & 7) ^ rV) * 8;
    const unsigned short* vpt = vT + ((size_t)bh * 64 + w * 32 + rV) * SEQ + cV8;

    // ---- swizzled read column offsets (const per thread) ----
    const int kcol  = (la ^ ((li >> 1) & 3)) * 8;          // K read chunk
    const int vcol0 = ((0 * 4 + la) ^ (li & 7)) * 8;       // V read, ks=0
    const int vcol1 = ((1 * 4 + la) ^ (li & 7)) * 8;       // V read, ks=1

    f32x4 accO[2][4];
    float lsum0 = 0.f, lsum1 = 0.f;             // row-sum for i=li, per iq
    #pragma unroll
    for (int iq = 0; iq < 2; iq++)
        #pragma unroll
        for (int dt = 0; dt < 4; dt++) accO[iq][dt] = (f32x4){0.f, 0.f, 0.f, 0.f};
    const int prow0 = w * 32 + li;
    const int prow1 = prow0 + 16;

    // prologue: issue async stage of tile 0 -> buf0 (drained at first barrier)
    ASYNC16(kpt,            &kt[0][(w * 32) * 32]);
    ASYNC16(kpt + 16 * 32,  &kt[0][(w * 32 + 16) * 32]);
    #pragma unroll
    for (int q = 0; q < 4; q++)
        ASYNC16(vpt + (size_t)q * 8 * SEQ, &vt[0][(w * 32 + q * 8) * 64]);

    #define ATTN_BODY(BUF, OTHER, JPRE)                                            \
    {                                                                              \
        VMDRAIN();                                                                 \
        __syncthreads();                                                           \
        const int jn = (JPRE) & 2047;                                              \
        ASYNC16(kpt + (size_t)jn * 32,           &kt[OTHER][(w * 32) * 32]);       \
        ASYNC16(kpt + (size_t)jn * 32 + 16 * 32, &kt[OTHER][(w * 32 + 16) * 32]);  \
        _Pragma("unroll")                                                          \
        for (int q = 0; q < 4; q++)                                                \
            ASYNC16(vpt + jn + (size_t)q * 8 * SEQ, &vt[OTHER][(w * 32 + q * 8) * 64]); \
        bf16x8 kf[4];                                                              \
        _Pragma("unroll")                                                          \
        for (int jt = 0; jt < 4; jt++)                                             \
            kf[jt] = *(const bf16x8*)&kt[BUF][(jt * 16 + li) * 32 + kcol];         \
        f32x4 sc0[4], sc1[4];                                                      \
        __builtin_amdgcn_s_setprio(1);                                             \
        _Pragma("unroll")                                                          \
        for (int jt = 0; jt < 4; jt++) {                                           \
            sc0[jt] = __builtin_amdgcn_mfma_f32_16x16x32_bf16(kf[jt], qf[0], (f32x4){0.f,0.f,0.f,0.f}, 0, 0, 0); \
            sc1[jt] = __builtin_amdgcn_mfma_f32_16x16x32_bf16(kf[jt], qf[1], (f32x4){0.f,0.f,0.f,0.f}, 0, 0, 0); \
        }                                                                          \
        __builtin_amdgcn_s_setprio(0);                                             \
        _Pragma("unroll")                                                          \
        for (int jt = 0; jt < 4; jt++) {                                           \
            float e0 = __builtin_amdgcn_exp2f(sc0[jt][0]);                         \
            float e1 = __builtin_amdgcn_exp2f(sc0[jt][1]);                         \
            float e2 = __builtin_amdgcn_exp2f(sc0[jt][2]);                         \
            float e3 = __builtin_amdgcn_exp2f(sc0[jt][3]);                         \
            lsum0 += (e0 + e1) + (e2 + e3);                                        \
            uint2 pk;                                                              \
            asm("v_cvt_pk_bf16_f32 %0, %1, %2" : "=v"(pk.x) : "v"(e0), "v"(e1));   \
            asm("v_cvt_pk_bf16_f32 %0, %1, %2" : "=v"(pk.y) : "v"(e2), "v"(e3));   \
            *(uint2*)&P[prow0 * 72 + jt * 16 + la * 4] = pk;                       \
        }                                                                          \
        _Pragma("unroll")                                                          \
        for (int jt = 0; jt < 4; jt++) {                                           \
            float e0 = __builtin_amdgcn_exp2f(sc1[jt][0]);                         \
            float e1 = __builtin_amdgcn_exp2f(sc1[jt][1]);                         \
            float e2 = __builtin_amdgcn_exp2f(sc1[jt][2]);                         \
            float e3 = __builtin_amdgcn_exp2f(sc1[jt][3]);                         \
            lsum1 += (e0 + e1) + (e2 + e3);                                        \
            uint2 pk;                                                              \
            asm("v_cvt_pk_bf16_f32 %0, %1, %2" : "=v"(pk.x) : "v"(e0), "v"(e1));   \
            asm("v_cvt_pk_bf16_f32 %0, %1, %2" : "=v"(pk.y) : "v"(e2), "v"(e3));   \
            *(uint2*)&P[prow1 * 72 + jt * 16 + la * 4] = pk;                       \
        }                                                                          \
        _Pragma("unroll")                                                          \
        for (int ks = 0; ks < 2; ks++) {                                           \
            const bf16x8 pf0 = *(const bf16x8*)&P[prow0 * 72 + ks * 32 + la * 8];  \
            const bf16x8 pf1 = *(const bf16x8*)&P[prow1 * 72 + ks * 32 + la * 8];  \
            const int vcol = ks ? vcol1 : vcol0;                                   \
            __builtin_amdgcn_s_setprio(1);                                         \
            _Pragma("unroll")                                                      \
            for (int dt = 0; dt < 4; dt++) {                                       \
                const bf16x8 vf = *(const bf16x8*)&vt[BUF][(dt * 16 + li) * 64 + vcol]; \
                accO[0][dt] = __builtin_amdgcn_mfma_f32_16x16x32_bf16(pf0, vf, accO[0][dt], 0, 0, 0); \
                accO[1][dt] = __builtin_amdgcn_mfma_f32_16x16x32_bf16(pf1, vf, accO[1][dt], 0, 0, 0); \
            }                                                                      \
            __builtin_amdgcn_s_setprio(0);                                         \
        }                                                                          \
    }

    for (int j0 = 0; j0 < SEQ; j0 += 128) {
        ATTN_BODY(0, 1, j0 + 64)
        ATTN_BODY(1, 0, j0 + 128)
    }
    #undef ATTN_BODY

    // drain the final tile's in-flight DMAs before LDS can be reassigned
    VMDRAIN();
    __syncthreads();

    // cross-la reduce: after this every lane holds l for i = w*32+iq*16+li
    lsum0 += __shfl_xor(lsum0, 16);
    lsum0 += __shfl_xor(lsum0, 32);
    lsum1 += __shfl_xor(lsum1, 16);
    lsum1 += __shfl_xor(lsum1, 32);

    // epilogue: accO rows are m = la*4+r; fetch l from the lane holding that i
    #pragma unroll
    for (int iq = 0; iq < 2; iq++) {
        const float ls = iq ? lsum1 : lsum0;
        float linv[4];
        #pragma unroll
        for (int r = 0; r < 4; r++)
            linv[r] = 1.f / __shfl(ls, la * 4 + r);
        #pragma unroll
        for (int dt = 0; dt < 4; dt++)
            #pragma unroll
            for (int r = 0; r < 4; r++) {
                const int row = b * SEQ + i0 + w * 32 + iq * 16 + la * 4 + r;
                ao[(size_t)row * 1024 + h * 64 + dt * 16 + li] = f2bf(accO[iq][dt][r] * linv[r]);
            }
    }
}

extern "C" void kernel_launch(void* const* d_in, const int* in_sizes, int n_in,
                              void* d_out, int out_size, void* d_ws, size_t ws_size,
                              hipStream_t stream) {
    const float* hs = (const float*)d_in[0];
    const float* Wq = (const float*)d_in[1];
    const float* bq = (const float*)d_in[2];
    const float* Wk = (const float*)d_in[3];
    const float* bk = (const float*)d_in[4];
    const float* Wv = (const float*)d_in[5];
    const float* bv = (const float*)d_in[6];
    const float* Wo = (const float*)d_in[7];
    const float* bo = (const float*)d_in[8];

    char* p = (char*)d_ws;                                        // 38 MB total
    unsigned short* hsb = (unsigned short*)(p);                   //  8 MB
    unsigned short* wT  = (unsigned short*)(p + 8388608u);        //  4 MB
    unsigned short* woT = (unsigned short*)(p + 12582912u);       //  2 MB
    float*          ball= (float*)(p + 14680064u);                //  8 KB
    unsigned short* qHb = (unsigned short*)(p + 14688256u);       //  4 MB
    unsigned short* kHb = (unsigned short*)(p + 18882560u);       //  4 MB
    unsigned short* vTb = (unsigned short*)(p + 23076864u);       //  8 MB
    unsigned short* ao  = (unsigned short*)(p + 31465472u);       //  8 MB

    prep_all<<<dim3(2824), 256, 0, stream>>>(hs, Wq, Wk, Wv, Wo, bq, bk, bv,
                                             hsb, wT, woT, ball);

    gemm_qkv<<<dim3(16, 32), 256, 0, stream>>>(hsb, wT, ball, qHb, kHb, vTb);

    attn_v15<<<dim3(1024), 128, 0, stream>>>(qHb, kHb, vTb, ao);

    gemm_out<<<dim3(8, 64), 256, 0, stream>>>(ao, woT, bo, (float*)d_out);
}